// Round 5
// baseline (306.922 us; speedup 1.0000x reference)
//
#include <hip/hip_runtime.h>
#include <stdint.h>

// Attention fwd: B=4 T=2048 D=1024 H=16 Dh=64.
// R5: flash q-tile 128->256 (wave owns 64 q): doubles FLOP per byte of K/V
// LDS traffic and per-tile compute (amortizes the structural barrier/vmcnt
// drain), grid 512 blocks = exactly 2/CU (single round, no tail).
// gemm_qkv gets __launch_bounds__(256,5) (VGPR cap 102 -> 5 blocks/CU).

typedef __attribute__((ext_vector_type(8))) short bf16x8;
typedef __attribute__((ext_vector_type(4))) float f32x4;

#define MFMA32 __builtin_amdgcn_mfma_f32_16x16x32_bf16

#if __has_builtin(__builtin_amdgcn_exp2f)
#define EXP2(x) __builtin_amdgcn_exp2f(x)
#else
#define EXP2(x) exp2f(x)   // host pass only
#endif

__device__ __forceinline__ unsigned short f2bf(float f) {
  union { float f; unsigned int u; } v; v.f = f;
  unsigned int r = v.u + 0x7FFFu + ((v.u >> 16) & 1u);  // RNE
  return (unsigned short)(r >> 16);
}

__device__ __forceinline__ void gl_lds16(const void* g, void* l) {
  __builtin_amdgcn_global_load_lds(
      (const __attribute__((address_space(1))) unsigned int*)g,
      (__attribute__((address_space(3))) unsigned int*)l, 16, 0, 0);
}

// truncating pack of two positive fp32 -> one u32 (two bf16)
__device__ __forceinline__ unsigned packbf2(float lo, float hi) {
  union { float f; unsigned u; } a, b; a.f = lo; b.f = hi;
  return __builtin_amdgcn_perm(b.u, a.u, 0x07060302u);
}

// LDS chunk swizzle for K/V tiles (conflict-free for permuted-row b128 reads)
__device__ __forceinline__ int rho(int r) { return (r & 3) | ((r >> 1) & 4); }

// ---------------- merged prep kernel ----------------
__device__ __forceinline__ void conv8(const float* __restrict__ src,
                                      unsigned short* __restrict__ dst, int i) {
  const float4* sp = (const float4*)src;
  float4 a = sp[2 * i], b = sp[2 * i + 1];
  union { unsigned short u[8]; uint4 v; } o;
  o.u[0] = f2bf(a.x); o.u[1] = f2bf(a.y); o.u[2] = f2bf(a.z); o.u[3] = f2bf(a.w);
  o.u[4] = f2bf(b.x); o.u[5] = f2bf(b.y); o.u[6] = f2bf(b.z); o.u[7] = f2bf(b.w);
  ((uint4*)dst)[i] = o.v;
}

__global__ __launch_bounds__(256) void prep_all(
    const float* __restrict__ x, const float* __restrict__ WQ,
    const float* __restrict__ WK, const float* __restrict__ WV,
    const float* __restrict__ WO, unsigned short* __restrict__ Xb,
    unsigned short* __restrict__ Wqkv, unsigned short* __restrict__ Wot) {
  const int bx = blockIdx.x, t = threadIdx.x;
  if (bx < 4096) {
    conv8(x, Xb, bx * 256 + t);
  } else if (bx < 4608) {
    conv8(WQ, Wqkv, (bx - 4096) * 256 + t);
  } else if (bx < 5120) {
    conv8(WK, Wqkv + 1048576, (bx - 4608) * 256 + t);
  } else if (bx < 5632) {
    conv8(WV, Wqkv + 2097152, (bx - 5120) * 256 + t);
  } else {
    // W_O [16][1024][64] fp32 -> Wot [d][h*64+k] bf16
    int tid = (bx - 5632) * 256 + t;
    int h = tid >> 13, rem = tid & 8191;
    int d = rem >> 3, c = rem & 7;
    const float4* sp = (const float4*)(WO + (size_t)h * 65536 + d * 64 + c * 8);
    float4 a = sp[0], e = sp[1];
    union { unsigned short u[8]; uint4 v; } o;
    o.u[0] = f2bf(a.x); o.u[1] = f2bf(a.y); o.u[2] = f2bf(a.z); o.u[3] = f2bf(a.w);
    o.u[4] = f2bf(e.x); o.u[5] = f2bf(e.y); o.u[6] = f2bf(e.z); o.u[7] = f2bf(e.w);
    *(uint4*)(Wot + (size_t)d * 1024 + h * 64 + c * 8) = o.v;
  }
}

// ---------------- shared GEMM mainloop ----------------
__device__ __forceinline__ void gemm_mainloop_1024(
    const unsigned short* __restrict__ A, const unsigned short* __restrict__ B,
    unsigned short* As, unsigned short* Bs, int m0, int n0, f32x4 acc[4][4]) {
  const int tid = threadIdx.x;
  const int lane = tid & 63, w = tid >> 6;
  const int quad = lane >> 4, l15 = lane & 15;
  const int wm = w & 1, wn = w >> 1;
  int srow[4], scl[4];
#pragma unroll
  for (int u = 0; u < 4; ++u) {
    int s = u * 256 + tid;
    srow[u] = s >> 3;
    scl[u] = ((s & 7) ^ ((s >> 3) & 7)) * 8;
  }
  for (int k0 = 0; k0 < 1024; k0 += 64) {
    __syncthreads();
#pragma unroll
    for (int u = 0; u < 4; ++u) {
      int s = u * 256 + tid;
      gl_lds16(A + (size_t)(m0 + srow[u]) * 1024 + k0 + scl[u], As + s * 8);
      gl_lds16(B + (size_t)(n0 + srow[u]) * 1024 + k0 + scl[u], Bs + s * 8);
    }
    __syncthreads();
    bf16x8 af[4][2], bfr[4][2];
#pragma unroll
    for (int i = 0; i < 4; ++i) {
      int ra = wm * 64 + i * 16 + l15;
      int rb = wn * 64 + i * 16 + l15;
#pragma unroll
      for (int c = 0; c < 2; ++c) {
        af[i][c]  = *(const bf16x8*)(As + ra * 64 + (((c * 4 + quad) ^ (ra & 7)) * 8));
        bfr[i][c] = *(const bf16x8*)(Bs + rb * 64 + (((c * 4 + quad) ^ (rb & 7)) * 8));
      }
    }
#pragma unroll
    for (int mi = 0; mi < 4; ++mi)
#pragma unroll
      for (int nj = 0; nj < 4; ++nj) {
        acc[mi][nj] = MFMA32(af[mi][0], bfr[nj][0], acc[mi][nj], 0, 0, 0);
        acc[mi][nj] = MFMA32(af[mi][1], bfr[nj][1], acc[mi][nj], 0, 0, 0);
      }
  }
}

// ---------------- QKV projection ----------------
__global__ __launch_bounds__(256, 5) void gemm_qkv(
    const unsigned short* __restrict__ Xb, const unsigned short* __restrict__ Wqkv,
    const float* __restrict__ bQ, const float* __restrict__ bK,
    const float* __restrict__ bV, unsigned short* __restrict__ Qg,
    unsigned short* __restrict__ Kg, unsigned int* __restrict__ Vpg) {
  __shared__ unsigned short As[128 * 64];
  __shared__ unsigned short Bs[128 * 64];
  const int tid = threadIdx.x, lane = tid & 63, w = tid >> 6;
  const int quad = lane >> 4, l15 = lane & 15;
  const int wm = w & 1, wn = w >> 1;
  const int m0 = blockIdx.x * 128, n0 = blockIdx.y * 128;
  f32x4 acc[4][4];
#pragma unroll
  for (int i = 0; i < 4; ++i)
#pragma unroll
    for (int j = 0; j < 4; ++j) acc[i][j] = (f32x4){0.f, 0.f, 0.f, 0.f};

  gemm_mainloop_1024(Xb, Wqkv, As, Bs, m0, n0, acc);

  const int type = n0 >> 10;
  const int nreg = n0 & 1023;
  const float* bias = (type == 0) ? bQ : (type == 1) ? bK : bV;
#pragma unroll
  for (int nj = 0; nj < 4; ++nj) {
    const int n_loc = nreg + wn * 64 + nj * 16 + l15;
    const int h = n_loc >> 6, kh = n_loc & 63;
    const float bv = bias[n_loc];
#pragma unroll
    for (int mi = 0; mi < 4; ++mi) {
      const int mb = m0 + wm * 64 + mi * 16 + quad * 4;
      const int b = mb >> 11, tb = mb & 2047;
      if (type == 2) {
        uint2 pk;
        pk.x = (unsigned)f2bf(acc[mi][nj][0] + bv) |
               ((unsigned)f2bf(acc[mi][nj][1] + bv) << 16);
        pk.y = (unsigned)f2bf(acc[mi][nj][2] + bv) |
               ((unsigned)f2bf(acc[mi][nj][3] + bv) << 16);
        *(uint2*)(Vpg + ((size_t)(b * 16 + h) * 64 + kh) * 1024 + (tb >> 1)) = pk;
      } else {
        unsigned short* dst =
            ((type == 0) ? Qg : Kg) + ((size_t)(b * 16 + h) * 2048 + tb) * 64 + kh;
        // Q pre-scaled by 1/sqrt(Dh) * log2(e) so flash uses exp2 directly
        const float sc = (type == 0) ? 0.18033688011112042f : 1.0f;
        dst[0]   = f2bf((acc[mi][nj][0] + bv) * sc);
        dst[64]  = f2bf((acc[mi][nj][1] + bv) * sc);
        dst[128] = f2bf((acc[mi][nj][2] + bv) * sc);
        dst[192] = f2bf((acc[mi][nj][3] + bv) * sc);
      }
    }
  }
}

// ---------------- flash attention ----------------
__device__ __forceinline__ void stage_kv(const unsigned short* __restrict__ Kb,
                                         const unsigned int* __restrict__ Vb,
                                         unsigned short* smem, int tid, int s0, int b) {
#pragma unroll
  for (int u = 0; u < 2; ++u) {
    int s = u * 256 + tid, row = s >> 3, g = (s & 7) ^ rho(row);
    gl_lds16(Kb + (size_t)(s0 + row) * 64 + g * 8, smem + b * 8192 + s * 8);
    gl_lds16(Vb + (size_t)row * 1024 + (s0 >> 1) + g * 4,
             smem + b * 8192 + 4096 + s * 8);
  }
}

// block: 256 q-rows of one (b,h); wave owns 64 q; k-tiles of 64, double-buffered.
__global__ __launch_bounds__(256, 2) void flash_attn(
    const unsigned short* __restrict__ Qg, const unsigned short* __restrict__ Kg,
    const unsigned int* __restrict__ Vpg, unsigned short* __restrict__ OH) {
  __shared__ unsigned short smem[16384];  // 32KB: [K0 8K][V0 8K][K1 8K][V1 8K]
  const int tid = threadIdx.x, lane = tid & 63, w = tid >> 6;
  const int quad = lane >> 4, l15 = lane & 15;
  const int qt = blockIdx.x, bh = blockIdx.y;

  const unsigned short* Qb = Qg + ((size_t)bh * 2048 + qt * 256) * 64;
  const unsigned short* Kb = Kg + (size_t)bh * 2048 * 64;
  const unsigned int*  Vb = Vpg + (size_t)bh * 64 * 1024;

  // stage Q (256 rows = 32KB, whole smem) — dead before tile 0
#pragma unroll
  for (int u = 0; u < 8; ++u) {
    int s = u * 256 + tid, row = s >> 3;
    gl_lds16(Qb + row * 64 + ((s & 7) ^ (row & 7)) * 8, smem + s * 8);
  }
  __syncthreads();

  bf16x8 qf[4][2];  // B-operand Q frags, hoisted for whole kernel
#pragma unroll
  for (int qi = 0; qi < 4; ++qi) {
    int row = w * 64 + qi * 16 + l15;
#pragma unroll
    for (int c = 0; c < 2; ++c)
      qf[qi][c] = *(const bf16x8*)(smem + row * 64 + (((c * 4 + quad) ^ (row & 7)) * 8));
  }
  __syncthreads();  // all waves done reading Q; safe to overwrite with K0/V0

  stage_kv(Kb, Vb, smem, tid, 0, 0);

  f32x4 o[4][4];
  float l_part[4] = {0.f, 0.f, 0.f, 0.f};
#pragma unroll
  for (int qi = 0; qi < 4; ++qi)
#pragma unroll
    for (int nj = 0; nj < 4; ++nj) o[qi][nj] = (f32x4){0.f, 0.f, 0.f, 0.f};

  for (int t = 0; t < 32; ++t) {
    __syncthreads();  // drains tile-t staging
    if (t < 31) stage_kv(Kb, Vb, smem, tid, (t + 1) * 64, (t + 1) & 1);
    const unsigned short* Kd = smem + (t & 1) * 8192;
    const unsigned short* Vd = Kd + 4096;

#pragma unroll
    for (int blk = 0; blk < 2; ++blk) {
      // V B-frags: Vt[dh = nj*16+l15][s = blk*32 + quad*8 .. +7] — one b128 each
      bf16x8 vb[4];
#pragma unroll
      for (int nj = 0; nj < 4; ++nj) {
        int vrow = nj * 16 + l15;
        vb[nj] = *(const bf16x8*)(Vd + vrow * 64 + (((blk * 4 + quad) ^ rho(vrow)) * 8));
      }
      union { unsigned u[4]; bf16x8 v; } pa[4];
#pragma unroll
      for (int v = 0; v < 2; ++v) {
        // permuted K rows: C/D row m maps to s = blk*32 + 8*quad + 4*v + reg
        int krow = blk * 32 + 8 * (l15 >> 2) + 4 * v + (l15 & 3);
        const unsigned short* kr = Kd + krow * 64;
        bf16x8 ka0 = *(const bf16x8*)(kr + ((quad ^ rho(krow)) * 8));
        bf16x8 ka1 = *(const bf16x8*)(kr + (((4 + quad) ^ rho(krow)) * 8));
#pragma unroll
        for (int qi = 0; qi < 4; ++qi) {
          f32x4 S = (f32x4){0.f, 0.f, 0.f, 0.f};
          S = MFMA32(ka0, qf[qi][0], S, 0, 0, 0);
          S = MFMA32(ka1, qf[qi][1], S, 0, 0, 0);
          float e0 = EXP2(S[0]), e1 = EXP2(S[1]), e2 = EXP2(S[2]), e3 = EXP2(S[3]);
          l_part[qi] += (e0 + e1) + (e2 + e3);
          pa[qi].u[2 * v] = packbf2(e0, e1);
          pa[qi].u[2 * v + 1] = packbf2(e2, e3);
        }
      }
#pragma unroll
      for (int nj = 0; nj < 4; ++nj)
#pragma unroll
        for (int qi = 0; qi < 4; ++qi)
          o[qi][nj] = MFMA32(pa[qi].v, vb[nj], o[qi][nj], 0, 0, 0);
    }
  }

  // l: cross-quad reduce once; normalize + store
  const int b = bh >> 4, h = bh & 15;
#pragma unroll
  for (int qi = 0; qi < 4; ++qi) {
    float l = l_part[qi];
    l += __shfl_xor(l, 16);
    l += __shfl_xor(l, 32);
    float linv = 1.0f / l;
#pragma unroll
    for (int r = 0; r < 4; ++r) {
      float lr = __shfl(linv, 4 * quad + r);  // l of q_local = 4*quad + r
      int trow = qt * 256 + w * 64 + qi * 16 + 4 * quad + r;
#pragma unroll
      for (int nj = 0; nj < 4; ++nj) {
        int col = h * 64 + nj * 16 + l15;
        OH[((size_t)b * 2048 + trow) * 1024 + col] = f2bf(o[qi][nj][r] * lr);
      }
    }
  }
}

// ---------------- output projection ----------------
__global__ __launch_bounds__(256) void gemm_o(
    const unsigned short* __restrict__ OHm, const unsigned short* __restrict__ Wot,
    const float* __restrict__ bO, float* __restrict__ Out) {
  __shared__ unsigned short As[128 * 64];
  __shared__ unsigned short Bs[128 * 64];
  const int tid = threadIdx.x, lane = tid & 63, w = tid >> 6;
  const int quad = lane >> 4, l15 = lane & 15;
  const int wm = w & 1, wn = w >> 1;
  const int m0 = blockIdx.x * 128, n0 = blockIdx.y * 128;
  f32x4 acc[4][4];
#pragma unroll
  for (int i = 0; i < 4; ++i)
#pragma unroll
    for (int j = 0; j < 4; ++j) acc[i][j] = (f32x4){0.f, 0.f, 0.f, 0.f};

  gemm_mainloop_1024(OHm, Wot, As, Bs, m0, n0, acc);

#pragma unroll
  for (int nj = 0; nj < 4; ++nj) {
    const int n = n0 + wn * 64 + nj * 16 + l15;
    const float bv = bO[n];
#pragma unroll
    for (int mi = 0; mi < 4; ++mi) {
      const int mb = m0 + wm * 64 + mi * 16 + quad * 4;
#pragma unroll
      for (int r = 0; r < 4; ++r)
        Out[(size_t)(mb + r) * 1024 + n] = acc[mi][nj][r] + bv;
    }
  }
}

// ---------------- launch ----------------
extern "C" void kernel_launch(void* const* d_in, const int* in_sizes, int n_in,
                              void* d_out, int out_size, void* d_ws, size_t ws_size,
                              hipStream_t stream) {
  const float* x  = (const float*)d_in[0];
  const float* WQ = (const float*)d_in[1];
  const float* bQ = (const float*)d_in[2];
  const float* WK = (const float*)d_in[3];
  const float* bK = (const float*)d_in[4];
  const float* WV = (const float*)d_in[5];
  const float* bV = (const float*)d_in[6];
  const float* WO = (const float*)d_in[7];
  const float* bO = (const float*)d_in[8];
  float* out = (float*)d_out;

  char* ws = (char*)d_ws;
  unsigned short* Xb   = (unsigned short*)(ws);                // 16 MB
  unsigned short* OH   = (unsigned short*)(ws);                // alias (Xb dead)
  unsigned short* Wqkv = (unsigned short*)(ws + 16777216);     // 6 MB
  unsigned short* Wot  = (unsigned short*)(ws + 23068672);     // 2 MB
  unsigned short* Qg   = (unsigned short*)(ws + 25165824);     // 16 MB
  unsigned short* Kg   = (unsigned short*)(ws + 41943040);     // 16 MB
  unsigned int*   Vpg  = (unsigned int*)  (ws + 58720256);     // 16 MB

  prep_all<<<6144, 256, 0, stream>>>(x, WQ, WK, WV, WO, Xb, Wqkv, Wot);

  dim3 g1(64, 24);
  gemm_qkv<<<g1, 256, 0, stream>>>(Xb, Wqkv, bQ, bK, bV, Qg, Kg, Vpg);
  dim3 g2(8, 64);
  flash_attn<<<g2, 256, 0, stream>>>(Qg, Kg, Vpg, OH);
  dim3 g3(64, 8);
  gemm_o<<<g3, 256, 0, stream>>>(OH, Wot, bO, out);
}

// Round 6
// 299.395 us; speedup vs baseline: 1.0251x; 1.0251x over previous
//
#include <hip/hip_runtime.h>
#include <stdint.h>

// Attention fwd: B=4 T=2048 D=1024 H=16 Dh=64.
// R6: revert gemm_qkv launch_bounds(256,5) (it forced VGPR 48 -> 65MB scratch
// spill, WRITE_SIZE 49.6->114.8MB); gemm_qkv tile 256x128 (two m-subtiles,
// 48KB LDS, B frags read once per k-step) to halve barrier-drain per FLOP.
// flash keeps R5 256-q tile (measured ~-30us).

typedef __attribute__((ext_vector_type(8))) short bf16x8;
typedef __attribute__((ext_vector_type(4))) float f32x4;

#define MFMA32 __builtin_amdgcn_mfma_f32_16x16x32_bf16

#if __has_builtin(__builtin_amdgcn_exp2f)
#define EXP2(x) __builtin_amdgcn_exp2f(x)
#else
#define EXP2(x) exp2f(x)   // host pass only
#endif

__device__ __forceinline__ unsigned short f2bf(float f) {
  union { float f; unsigned int u; } v; v.f = f;
  unsigned int r = v.u + 0x7FFFu + ((v.u >> 16) & 1u);  // RNE
  return (unsigned short)(r >> 16);
}

__device__ __forceinline__ void gl_lds16(const void* g, void* l) {
  __builtin_amdgcn_global_load_lds(
      (const __attribute__((address_space(1))) unsigned int*)g,
      (__attribute__((address_space(3))) unsigned int*)l, 16, 0, 0);
}

// truncating pack of two positive fp32 -> one u32 (two bf16)
__device__ __forceinline__ unsigned packbf2(float lo, float hi) {
  union { float f; unsigned u; } a, b; a.f = lo; b.f = hi;
  return __builtin_amdgcn_perm(b.u, a.u, 0x07060302u);
}

// LDS chunk swizzle for K/V tiles (conflict-free for permuted-row b128 reads)
__device__ __forceinline__ int rho(int r) { return (r & 3) | ((r >> 1) & 4); }

// ---------------- merged prep kernel ----------------
__device__ __forceinline__ void conv8(const float* __restrict__ src,
                                      unsigned short* __restrict__ dst, int i) {
  const float4* sp = (const float4*)src;
  float4 a = sp[2 * i], b = sp[2 * i + 1];
  union { unsigned short u[8]; uint4 v; } o;
  o.u[0] = f2bf(a.x); o.u[1] = f2bf(a.y); o.u[2] = f2bf(a.z); o.u[3] = f2bf(a.w);
  o.u[4] = f2bf(b.x); o.u[5] = f2bf(b.y); o.u[6] = f2bf(b.z); o.u[7] = f2bf(b.w);
  ((uint4*)dst)[i] = o.v;
}

__global__ __launch_bounds__(256) void prep_all(
    const float* __restrict__ x, const float* __restrict__ WQ,
    const float* __restrict__ WK, const float* __restrict__ WV,
    const float* __restrict__ WO, unsigned short* __restrict__ Xb,
    unsigned short* __restrict__ Wqkv, unsigned short* __restrict__ Wot) {
  const int bx = blockIdx.x, t = threadIdx.x;
  if (bx < 4096) {
    conv8(x, Xb, bx * 256 + t);
  } else if (bx < 4608) {
    conv8(WQ, Wqkv, (bx - 4096) * 256 + t);
  } else if (bx < 5120) {
    conv8(WK, Wqkv + 1048576, (bx - 4608) * 256 + t);
  } else if (bx < 5632) {
    conv8(WV, Wqkv + 2097152, (bx - 5120) * 256 + t);
  } else {
    // W_O [16][1024][64] fp32 -> Wot [d][h*64+k] bf16
    int tid = (bx - 5632) * 256 + t;
    int h = tid >> 13, rem = tid & 8191;
    int d = rem >> 3, c = rem & 7;
    const float4* sp = (const float4*)(WO + (size_t)h * 65536 + d * 64 + c * 8);
    float4 a = sp[0], e = sp[1];
    union { unsigned short u[8]; uint4 v; } o;
    o.u[0] = f2bf(a.x); o.u[1] = f2bf(a.y); o.u[2] = f2bf(a.z); o.u[3] = f2bf(a.w);
    o.u[4] = f2bf(e.x); o.u[5] = f2bf(e.y); o.u[6] = f2bf(e.z); o.u[7] = f2bf(e.w);
    *(uint4*)(Wot + (size_t)d * 1024 + h * 64 + c * 8) = o.v;
  }
}

// ---------------- shared GEMM mainloop (128x128, for gemm_o) ----------------
__device__ __forceinline__ void gemm_mainloop_1024(
    const unsigned short* __restrict__ A, const unsigned short* __restrict__ B,
    unsigned short* As, unsigned short* Bs, int m0, int n0, f32x4 acc[4][4]) {
  const int tid = threadIdx.x;
  const int lane = tid & 63, w = tid >> 6;
  const int quad = lane >> 4, l15 = lane & 15;
  const int wm = w & 1, wn = w >> 1;
  for (int k0 = 0; k0 < 1024; k0 += 64) {
    __syncthreads();
#pragma unroll
    for (int u = 0; u < 4; ++u) {
      int s = u * 256 + tid, row = s >> 3;
      int cl = ((s & 7) ^ (row & 7)) * 8;
      gl_lds16(A + (size_t)(m0 + row) * 1024 + k0 + cl, As + s * 8);
      gl_lds16(B + (size_t)(n0 + row) * 1024 + k0 + cl, Bs + s * 8);
    }
    __syncthreads();
    bf16x8 af[4][2], bfr[4][2];
#pragma unroll
    for (int i = 0; i < 4; ++i) {
      int ra = wm * 64 + i * 16 + l15;
      int rb = wn * 64 + i * 16 + l15;
#pragma unroll
      for (int c = 0; c < 2; ++c) {
        af[i][c]  = *(const bf16x8*)(As + ra * 64 + (((c * 4 + quad) ^ (ra & 7)) * 8));
        bfr[i][c] = *(const bf16x8*)(Bs + rb * 64 + (((c * 4 + quad) ^ (rb & 7)) * 8));
      }
    }
#pragma unroll
    for (int mi = 0; mi < 4; ++mi)
#pragma unroll
      for (int nj = 0; nj < 4; ++nj) {
        acc[mi][nj] = MFMA32(af[mi][0], bfr[nj][0], acc[mi][nj], 0, 0, 0);
        acc[mi][nj] = MFMA32(af[mi][1], bfr[nj][1], acc[mi][nj], 0, 0, 0);
      }
  }
}

// ---------------- QKV projection (256x128 tile) ----------------
__global__ __launch_bounds__(256) void gemm_qkv(
    const unsigned short* __restrict__ Xb, const unsigned short* __restrict__ Wqkv,
    const float* __restrict__ bQ, const float* __restrict__ bK,
    const float* __restrict__ bV, unsigned short* __restrict__ Qg,
    unsigned short* __restrict__ Kg, unsigned int* __restrict__ Vpg) {
  __shared__ unsigned short As[256 * 64];  // 32KB
  __shared__ unsigned short Bs[128 * 64];  // 16KB
  const int tid = threadIdx.x, lane = tid & 63, w = tid >> 6;
  const int quad = lane >> 4, l15 = lane & 15;
  const int wm = w & 1, wn = w >> 1;
  const int m0 = blockIdx.x * 256, n0 = blockIdx.y * 128;
  f32x4 acc[2][4][4];
#pragma unroll
  for (int mt = 0; mt < 2; ++mt)
#pragma unroll
    for (int i = 0; i < 4; ++i)
#pragma unroll
      for (int j = 0; j < 4; ++j) acc[mt][i][j] = (f32x4){0.f, 0.f, 0.f, 0.f};

  for (int k0 = 0; k0 < 1024; k0 += 64) {
    __syncthreads();
#pragma unroll
    for (int u = 0; u < 8; ++u) {   // A: 256 rows
      int s = u * 256 + tid, row = s >> 3;
      int cl = ((s & 7) ^ (row & 7)) * 8;
      gl_lds16(Xb + (size_t)(m0 + row) * 1024 + k0 + cl, As + s * 8);
    }
#pragma unroll
    for (int u = 0; u < 4; ++u) {   // B: 128 rows
      int s = u * 256 + tid, row = s >> 3;
      int cl = ((s & 7) ^ (row & 7)) * 8;
      gl_lds16(Wqkv + (size_t)(n0 + row) * 1024 + k0 + cl, Bs + s * 8);
    }
    __syncthreads();
    bf16x8 bfr[4][2];
#pragma unroll
    for (int i = 0; i < 4; ++i) {
      int rb = wn * 64 + i * 16 + l15;
#pragma unroll
      for (int c = 0; c < 2; ++c)
        bfr[i][c] = *(const bf16x8*)(Bs + rb * 64 + (((c * 4 + quad) ^ (rb & 7)) * 8));
    }
#pragma unroll
    for (int mt = 0; mt < 2; ++mt) {
      bf16x8 af[4][2];
#pragma unroll
      for (int i = 0; i < 4; ++i) {
        int ra = mt * 128 + wm * 64 + i * 16 + l15;
#pragma unroll
        for (int c = 0; c < 2; ++c)
          af[i][c] = *(const bf16x8*)(As + ra * 64 + (((c * 4 + quad) ^ (ra & 7)) * 8));
      }
#pragma unroll
      for (int mi = 0; mi < 4; ++mi)
#pragma unroll
        for (int nj = 0; nj < 4; ++nj) {
          acc[mt][mi][nj] = MFMA32(af[mi][0], bfr[nj][0], acc[mt][mi][nj], 0, 0, 0);
          acc[mt][mi][nj] = MFMA32(af[mi][1], bfr[nj][1], acc[mt][mi][nj], 0, 0, 0);
        }
    }
  }

  const int type = n0 >> 10;
  const int nreg = n0 & 1023;
  const float* bias = (type == 0) ? bQ : (type == 1) ? bK : bV;
#pragma unroll
  for (int nj = 0; nj < 4; ++nj) {
    const int n_loc = nreg + wn * 64 + nj * 16 + l15;
    const int h = n_loc >> 6, kh = n_loc & 63;
    const float bv = bias[n_loc];
#pragma unroll
    for (int mt = 0; mt < 2; ++mt)
#pragma unroll
      for (int mi = 0; mi < 4; ++mi) {
        const int mb = m0 + mt * 128 + wm * 64 + mi * 16 + quad * 4;
        const int b = mb >> 11, tb = mb & 2047;
        if (type == 2) {
          uint2 pk;
          pk.x = (unsigned)f2bf(acc[mt][mi][nj][0] + bv) |
                 ((unsigned)f2bf(acc[mt][mi][nj][1] + bv) << 16);
          pk.y = (unsigned)f2bf(acc[mt][mi][nj][2] + bv) |
                 ((unsigned)f2bf(acc[mt][mi][nj][3] + bv) << 16);
          *(uint2*)(Vpg + ((size_t)(b * 16 + h) * 64 + kh) * 1024 + (tb >> 1)) = pk;
        } else {
          unsigned short* dst =
              ((type == 0) ? Qg : Kg) + ((size_t)(b * 16 + h) * 2048 + tb) * 64 + kh;
          // Q pre-scaled by 1/sqrt(Dh) * log2(e) so flash uses exp2 directly
          const float sc = (type == 0) ? 0.18033688011112042f : 1.0f;
          dst[0]   = f2bf((acc[mt][mi][nj][0] + bv) * sc);
          dst[64]  = f2bf((acc[mt][mi][nj][1] + bv) * sc);
          dst[128] = f2bf((acc[mt][mi][nj][2] + bv) * sc);
          dst[192] = f2bf((acc[mt][mi][nj][3] + bv) * sc);
        }
      }
  }
}

// ---------------- flash attention ----------------
__device__ __forceinline__ void stage_kv(const unsigned short* __restrict__ Kb,
                                         const unsigned int* __restrict__ Vb,
                                         unsigned short* smem, int tid, int s0, int b) {
#pragma unroll
  for (int u = 0; u < 2; ++u) {
    int s = u * 256 + tid, row = s >> 3, g = (s & 7) ^ rho(row);
    gl_lds16(Kb + (size_t)(s0 + row) * 64 + g * 8, smem + b * 8192 + s * 8);
    gl_lds16(Vb + (size_t)row * 1024 + (s0 >> 1) + g * 4,
             smem + b * 8192 + 4096 + s * 8);
  }
}

// block: 256 q-rows of one (b,h); wave owns 64 q; k-tiles of 64, double-buffered.
__global__ __launch_bounds__(256, 2) void flash_attn(
    const unsigned short* __restrict__ Qg, const unsigned short* __restrict__ Kg,
    const unsigned int* __restrict__ Vpg, unsigned short* __restrict__ OH) {
  __shared__ unsigned short smem[16384];  // 32KB: [K0 8K][V0 8K][K1 8K][V1 8K]
  const int tid = threadIdx.x, lane = tid & 63, w = tid >> 6;
  const int quad = lane >> 4, l15 = lane & 15;
  const int qt = blockIdx.x, bh = blockIdx.y;

  const unsigned short* Qb = Qg + ((size_t)bh * 2048 + qt * 256) * 64;
  const unsigned short* Kb = Kg + (size_t)bh * 2048 * 64;
  const unsigned int*  Vb = Vpg + (size_t)bh * 64 * 1024;

  // stage Q (256 rows = 32KB, whole smem) — dead before tile 0
#pragma unroll
  for (int u = 0; u < 8; ++u) {
    int s = u * 256 + tid, row = s >> 3;
    gl_lds16(Qb + row * 64 + ((s & 7) ^ (row & 7)) * 8, smem + s * 8);
  }
  __syncthreads();

  bf16x8 qf[4][2];  // B-operand Q frags, hoisted for whole kernel
#pragma unroll
  for (int qi = 0; qi < 4; ++qi) {
    int row = w * 64 + qi * 16 + l15;
#pragma unroll
    for (int c = 0; c < 2; ++c)
      qf[qi][c] = *(const bf16x8*)(smem + row * 64 + (((c * 4 + quad) ^ (row & 7)) * 8));
  }
  __syncthreads();  // all waves done reading Q; safe to overwrite with K0/V0

  stage_kv(Kb, Vb, smem, tid, 0, 0);

  f32x4 o[4][4];
  float l_part[4] = {0.f, 0.f, 0.f, 0.f};
#pragma unroll
  for (int qi = 0; qi < 4; ++qi)
#pragma unroll
    for (int nj = 0; nj < 4; ++nj) o[qi][nj] = (f32x4){0.f, 0.f, 0.f, 0.f};

  for (int t = 0; t < 32; ++t) {
    __syncthreads();  // drains tile-t staging
    if (t < 31) stage_kv(Kb, Vb, smem, tid, (t + 1) * 64, (t + 1) & 1);
    const unsigned short* Kd = smem + (t & 1) * 8192;
    const unsigned short* Vd = Kd + 4096;

#pragma unroll
    for (int blk = 0; blk < 2; ++blk) {
      // V B-frags: Vt[dh = nj*16+l15][s = blk*32 + quad*8 .. +7] — one b128 each
      bf16x8 vb[4];
#pragma unroll
      for (int nj = 0; nj < 4; ++nj) {
        int vrow = nj * 16 + l15;
        vb[nj] = *(const bf16x8*)(Vd + vrow * 64 + (((blk * 4 + quad) ^ rho(vrow)) * 8));
      }
      union { unsigned u[4]; bf16x8 v; } pa[4];
#pragma unroll
      for (int v = 0; v < 2; ++v) {
        // permuted K rows: C/D row m maps to s = blk*32 + 8*quad + 4*v + reg
        int krow = blk * 32 + 8 * (l15 >> 2) + 4 * v + (l15 & 3);
        const unsigned short* kr = Kd + krow * 64;
        bf16x8 ka0 = *(const bf16x8*)(kr + ((quad ^ rho(krow)) * 8));
        bf16x8 ka1 = *(const bf16x8*)(kr + (((4 + quad) ^ rho(krow)) * 8));
#pragma unroll
        for (int qi = 0; qi < 4; ++qi) {
          f32x4 S = (f32x4){0.f, 0.f, 0.f, 0.f};
          S = MFMA32(ka0, qf[qi][0], S, 0, 0, 0);
          S = MFMA32(ka1, qf[qi][1], S, 0, 0, 0);
          float e0 = EXP2(S[0]), e1 = EXP2(S[1]), e2 = EXP2(S[2]), e3 = EXP2(S[3]);
          l_part[qi] += (e0 + e1) + (e2 + e3);
          pa[qi].u[2 * v] = packbf2(e0, e1);
          pa[qi].u[2 * v + 1] = packbf2(e2, e3);
        }
      }
#pragma unroll
      for (int nj = 0; nj < 4; ++nj)
#pragma unroll
        for (int qi = 0; qi < 4; ++qi)
          o[qi][nj] = MFMA32(pa[qi].v, vb[nj], o[qi][nj], 0, 0, 0);
    }
  }

  // l: cross-quad reduce once; normalize + store
  const int b = bh >> 4, h = bh & 15;
#pragma unroll
  for (int qi = 0; qi < 4; ++qi) {
    float l = l_part[qi];
    l += __shfl_xor(l, 16);
    l += __shfl_xor(l, 32);
    float linv = 1.0f / l;
#pragma unroll
    for (int r = 0; r < 4; ++r) {
      float lr = __shfl(linv, 4 * quad + r);  // l of q_local = 4*quad + r
      int trow = qt * 256 + w * 64 + qi * 16 + 4 * quad + r;
#pragma unroll
      for (int nj = 0; nj < 4; ++nj) {
        int col = h * 64 + nj * 16 + l15;
        OH[((size_t)b * 2048 + trow) * 1024 + col] = f2bf(o[qi][nj][r] * lr);
      }
    }
  }
}

// ---------------- output projection ----------------
__global__ __launch_bounds__(256) void gemm_o(
    const unsigned short* __restrict__ OHm, const unsigned short* __restrict__ Wot,
    const float* __restrict__ bO, float* __restrict__ Out) {
  __shared__ unsigned short As[128 * 64];
  __shared__ unsigned short Bs[128 * 64];
  const int tid = threadIdx.x, lane = tid & 63, w = tid >> 6;
  const int quad = lane >> 4, l15 = lane & 15;
  const int wm = w & 1, wn = w >> 1;
  const int m0 = blockIdx.x * 128, n0 = blockIdx.y * 128;
  f32x4 acc[4][4];
#pragma unroll
  for (int i = 0; i < 4; ++i)
#pragma unroll
    for (int j = 0; j < 4; ++j) acc[i][j] = (f32x4){0.f, 0.f, 0.f, 0.f};

  gemm_mainloop_1024(OHm, Wot, As, Bs, m0, n0, acc);

#pragma unroll
  for (int nj = 0; nj < 4; ++nj) {
    const int n = n0 + wn * 64 + nj * 16 + l15;
    const float bv = bO[n];
#pragma unroll
    for (int mi = 0; mi < 4; ++mi) {
      const int mb = m0 + wm * 64 + mi * 16 + quad * 4;
#pragma unroll
      for (int r = 0; r < 4; ++r)
        Out[(size_t)(mb + r) * 1024 + n] = acc[mi][nj][r] + bv;
    }
  }
}

// ---------------- launch ----------------
extern "C" void kernel_launch(void* const* d_in, const int* in_sizes, int n_in,
                              void* d_out, int out_size, void* d_ws, size_t ws_size,
                              hipStream_t stream) {
  const float* x  = (const float*)d_in[0];
  const float* WQ = (const float*)d_in[1];
  const float* bQ = (const float*)d_in[2];
  const float* WK = (const float*)d_in[3];
  const float* bK = (const float*)d_in[4];
  const float* WV = (const float*)d_in[5];
  const float* bV = (const float*)d_in[6];
  const float* WO = (const float*)d_in[7];
  const float* bO = (const float*)d_in[8];
  float* out = (float*)d_out;

  char* ws = (char*)d_ws;
  unsigned short* Xb   = (unsigned short*)(ws);                // 16 MB
  unsigned short* OH   = (unsigned short*)(ws);                // alias (Xb dead)
  unsigned short* Wqkv = (unsigned short*)(ws + 16777216);     // 6 MB
  unsigned short* Wot  = (unsigned short*)(ws + 23068672);     // 2 MB
  unsigned short* Qg   = (unsigned short*)(ws + 25165824);     // 16 MB
  unsigned short* Kg   = (unsigned short*)(ws + 41943040);     // 16 MB
  unsigned int*   Vpg  = (unsigned int*)  (ws + 58720256);     // 16 MB

  prep_all<<<6144, 256, 0, stream>>>(x, WQ, WK, WV, WO, Xb, Wqkv, Wot);

  dim3 g1(32, 24);
  gemm_qkv<<<g1, 256, 0, stream>>>(Xb, Wqkv, bQ, bK, bV, Qg, Kg, Vpg);
  dim3 g2(8, 64);
  flash_attn<<<g2, 256, 0, stream>>>(Qg, Kg, Vpg, OH);
  dim3 g3(64, 8);
  gemm_o<<<g3, 256, 0, stream>>>(OH, Wot, bO, out);
}

// Round 7
// 273.230 us; speedup vs baseline: 1.1233x; 1.0958x over previous
//
#include <hip/hip_runtime.h>
#include <stdint.h>

// Attention fwd: B=4 T=2048 D=1024 H=16 Dh=64.
// R7: recombine best-measured variants — gemm_qkv reverted to R4's 128x128
// tile (VGPR 112 -> 4 blocks/CU; R5's forced 5/CU spilled, R6's 256x128 tile
// dropped to 2/CU and regressed 78.5->108.6us) + R5 flash (256-q tile,
// all-MFMA32, rho-swizzle, exp2) + gemm_o + merged prep.

typedef __attribute__((ext_vector_type(8))) short bf16x8;
typedef __attribute__((ext_vector_type(4))) float f32x4;

#define MFMA32 __builtin_amdgcn_mfma_f32_16x16x32_bf16

#if __has_builtin(__builtin_amdgcn_exp2f)
#define EXP2(x) __builtin_amdgcn_exp2f(x)
#else
#define EXP2(x) exp2f(x)   // host pass only
#endif

__device__ __forceinline__ unsigned short f2bf(float f) {
  union { float f; unsigned int u; } v; v.f = f;
  unsigned int r = v.u + 0x7FFFu + ((v.u >> 16) & 1u);  // RNE
  return (unsigned short)(r >> 16);
}

__device__ __forceinline__ void gl_lds16(const void* g, void* l) {
  __builtin_amdgcn_global_load_lds(
      (const __attribute__((address_space(1))) unsigned int*)g,
      (__attribute__((address_space(3))) unsigned int*)l, 16, 0, 0);
}

// truncating pack of two positive fp32 -> one u32 (two bf16)
__device__ __forceinline__ unsigned packbf2(float lo, float hi) {
  union { float f; unsigned u; } a, b; a.f = lo; b.f = hi;
  return __builtin_amdgcn_perm(b.u, a.u, 0x07060302u);
}

// LDS chunk swizzle for K/V tiles (conflict-free for permuted-row b128 reads)
__device__ __forceinline__ int rho(int r) { return (r & 3) | ((r >> 1) & 4); }

// ---------------- merged prep kernel ----------------
__device__ __forceinline__ void conv8(const float* __restrict__ src,
                                      unsigned short* __restrict__ dst, int i) {
  const float4* sp = (const float4*)src;
  float4 a = sp[2 * i], b = sp[2 * i + 1];
  union { unsigned short u[8]; uint4 v; } o;
  o.u[0] = f2bf(a.x); o.u[1] = f2bf(a.y); o.u[2] = f2bf(a.z); o.u[3] = f2bf(a.w);
  o.u[4] = f2bf(b.x); o.u[5] = f2bf(b.y); o.u[6] = f2bf(b.z); o.u[7] = f2bf(b.w);
  ((uint4*)dst)[i] = o.v;
}

__global__ __launch_bounds__(256) void prep_all(
    const float* __restrict__ x, const float* __restrict__ WQ,
    const float* __restrict__ WK, const float* __restrict__ WV,
    const float* __restrict__ WO, unsigned short* __restrict__ Xb,
    unsigned short* __restrict__ Wqkv, unsigned short* __restrict__ Wot) {
  const int bx = blockIdx.x, t = threadIdx.x;
  if (bx < 4096) {
    conv8(x, Xb, bx * 256 + t);
  } else if (bx < 4608) {
    conv8(WQ, Wqkv, (bx - 4096) * 256 + t);
  } else if (bx < 5120) {
    conv8(WK, Wqkv + 1048576, (bx - 4608) * 256 + t);
  } else if (bx < 5632) {
    conv8(WV, Wqkv + 2097152, (bx - 5120) * 256 + t);
  } else {
    // W_O [16][1024][64] fp32 -> Wot [d][h*64+k] bf16
    int tid = (bx - 5632) * 256 + t;
    int h = tid >> 13, rem = tid & 8191;
    int d = rem >> 3, c = rem & 7;
    const float4* sp = (const float4*)(WO + (size_t)h * 65536 + d * 64 + c * 8);
    float4 a = sp[0], e = sp[1];
    union { unsigned short u[8]; uint4 v; } o;
    o.u[0] = f2bf(a.x); o.u[1] = f2bf(a.y); o.u[2] = f2bf(a.z); o.u[3] = f2bf(a.w);
    o.u[4] = f2bf(e.x); o.u[5] = f2bf(e.y); o.u[6] = f2bf(e.z); o.u[7] = f2bf(e.w);
    *(uint4*)(Wot + (size_t)d * 1024 + h * 64 + c * 8) = o.v;
  }
}

// ---------------- shared GEMM mainloop (128x128) ----------------
__device__ __forceinline__ void gemm_mainloop_1024(
    const unsigned short* __restrict__ A, const unsigned short* __restrict__ B,
    unsigned short* As, unsigned short* Bs, int m0, int n0, f32x4 acc[4][4]) {
  const int tid = threadIdx.x;
  const int lane = tid & 63, w = tid >> 6;
  const int quad = lane >> 4, l15 = lane & 15;
  const int wm = w & 1, wn = w >> 1;
  int srow[4], scl[4];
#pragma unroll
  for (int u = 0; u < 4; ++u) {
    int s = u * 256 + tid;
    srow[u] = s >> 3;
    scl[u] = ((s & 7) ^ ((s >> 3) & 7)) * 8;
  }
  for (int k0 = 0; k0 < 1024; k0 += 64) {
    __syncthreads();
#pragma unroll
    for (int u = 0; u < 4; ++u) {
      int s = u * 256 + tid;
      gl_lds16(A + (size_t)(m0 + srow[u]) * 1024 + k0 + scl[u], As + s * 8);
      gl_lds16(B + (size_t)(n0 + srow[u]) * 1024 + k0 + scl[u], Bs + s * 8);
    }
    __syncthreads();
    bf16x8 af[4][2], bfr[4][2];
#pragma unroll
    for (int i = 0; i < 4; ++i) {
      int ra = wm * 64 + i * 16 + l15;
      int rb = wn * 64 + i * 16 + l15;
#pragma unroll
      for (int c = 0; c < 2; ++c) {
        af[i][c]  = *(const bf16x8*)(As + ra * 64 + (((c * 4 + quad) ^ (ra & 7)) * 8));
        bfr[i][c] = *(const bf16x8*)(Bs + rb * 64 + (((c * 4 + quad) ^ (rb & 7)) * 8));
      }
    }
#pragma unroll
    for (int mi = 0; mi < 4; ++mi)
#pragma unroll
      for (int nj = 0; nj < 4; ++nj) {
        acc[mi][nj] = MFMA32(af[mi][0], bfr[nj][0], acc[mi][nj], 0, 0, 0);
        acc[mi][nj] = MFMA32(af[mi][1], bfr[nj][1], acc[mi][nj], 0, 0, 0);
      }
  }
}

// ---------------- QKV projection (128x128 tile, R4 form) ----------------
__global__ __launch_bounds__(256) void gemm_qkv(
    const unsigned short* __restrict__ Xb, const unsigned short* __restrict__ Wqkv,
    const float* __restrict__ bQ, const float* __restrict__ bK,
    const float* __restrict__ bV, unsigned short* __restrict__ Qg,
    unsigned short* __restrict__ Kg, unsigned int* __restrict__ Vpg) {
  __shared__ unsigned short As[128 * 64];
  __shared__ unsigned short Bs[128 * 64];
  const int tid = threadIdx.x, lane = tid & 63, w = tid >> 6;
  const int quad = lane >> 4, l15 = lane & 15;
  const int wm = w & 1, wn = w >> 1;
  const int m0 = blockIdx.x * 128, n0 = blockIdx.y * 128;
  f32x4 acc[4][4];
#pragma unroll
  for (int i = 0; i < 4; ++i)
#pragma unroll
    for (int j = 0; j < 4; ++j) acc[i][j] = (f32x4){0.f, 0.f, 0.f, 0.f};

  gemm_mainloop_1024(Xb, Wqkv, As, Bs, m0, n0, acc);

  const int type = n0 >> 10;
  const int nreg = n0 & 1023;
  const float* bias = (type == 0) ? bQ : (type == 1) ? bK : bV;
#pragma unroll
  for (int nj = 0; nj < 4; ++nj) {
    const int n_loc = nreg + wn * 64 + nj * 16 + l15;
    const int h = n_loc >> 6, kh = n_loc & 63;
    const float bv = bias[n_loc];
#pragma unroll
    for (int mi = 0; mi < 4; ++mi) {
      const int mb = m0 + wm * 64 + mi * 16 + quad * 4;
      const int b = mb >> 11, tb = mb & 2047;
      if (type == 2) {
        uint2 pk;
        pk.x = (unsigned)f2bf(acc[mi][nj][0] + bv) |
               ((unsigned)f2bf(acc[mi][nj][1] + bv) << 16);
        pk.y = (unsigned)f2bf(acc[mi][nj][2] + bv) |
               ((unsigned)f2bf(acc[mi][nj][3] + bv) << 16);
        *(uint2*)(Vpg + ((size_t)(b * 16 + h) * 64 + kh) * 1024 + (tb >> 1)) = pk;
      } else {
        unsigned short* dst =
            ((type == 0) ? Qg : Kg) + ((size_t)(b * 16 + h) * 2048 + tb) * 64 + kh;
        // Q pre-scaled by 1/sqrt(Dh) * log2(e) so flash uses exp2 directly
        const float sc = (type == 0) ? 0.18033688011112042f : 1.0f;
        dst[0]   = f2bf((acc[mi][nj][0] + bv) * sc);
        dst[64]  = f2bf((acc[mi][nj][1] + bv) * sc);
        dst[128] = f2bf((acc[mi][nj][2] + bv) * sc);
        dst[192] = f2bf((acc[mi][nj][3] + bv) * sc);
      }
    }
  }
}

// ---------------- flash attention ----------------
__device__ __forceinline__ void stage_kv(const unsigned short* __restrict__ Kb,
                                         const unsigned int* __restrict__ Vb,
                                         unsigned short* smem, int tid, int s0, int b) {
#pragma unroll
  for (int u = 0; u < 2; ++u) {
    int s = u * 256 + tid, row = s >> 3, g = (s & 7) ^ rho(row);
    gl_lds16(Kb + (size_t)(s0 + row) * 64 + g * 8, smem + b * 8192 + s * 8);
    gl_lds16(Vb + (size_t)row * 1024 + (s0 >> 1) + g * 4,
             smem + b * 8192 + 4096 + s * 8);
  }
}

// block: 256 q-rows of one (b,h); wave owns 64 q; k-tiles of 64, double-buffered.
__global__ __launch_bounds__(256, 2) void flash_attn(
    const unsigned short* __restrict__ Qg, const unsigned short* __restrict__ Kg,
    const unsigned int* __restrict__ Vpg, unsigned short* __restrict__ OH) {
  __shared__ unsigned short smem[16384];  // 32KB: [K0 8K][V0 8K][K1 8K][V1 8K]
  const int tid = threadIdx.x, lane = tid & 63, w = tid >> 6;
  const int quad = lane >> 4, l15 = lane & 15;
  const int qt = blockIdx.x, bh = blockIdx.y;

  const unsigned short* Qb = Qg + ((size_t)bh * 2048 + qt * 256) * 64;
  const unsigned short* Kb = Kg + (size_t)bh * 2048 * 64;
  const unsigned int*  Vb = Vpg + (size_t)bh * 64 * 1024;

  // stage Q (256 rows = 32KB, whole smem) — dead before tile 0
#pragma unroll
  for (int u = 0; u < 8; ++u) {
    int s = u * 256 + tid, row = s >> 3;
    gl_lds16(Qb + row * 64 + ((s & 7) ^ (row & 7)) * 8, smem + s * 8);
  }
  __syncthreads();

  bf16x8 qf[4][2];  // B-operand Q frags, hoisted for whole kernel
#pragma unroll
  for (int qi = 0; qi < 4; ++qi) {
    int row = w * 64 + qi * 16 + l15;
#pragma unroll
    for (int c = 0; c < 2; ++c)
      qf[qi][c] = *(const bf16x8*)(smem + row * 64 + (((c * 4 + quad) ^ (row & 7)) * 8));
  }
  __syncthreads();  // all waves done reading Q; safe to overwrite with K0/V0

  stage_kv(Kb, Vb, smem, tid, 0, 0);

  f32x4 o[4][4];
  float l_part[4] = {0.f, 0.f, 0.f, 0.f};
#pragma unroll
  for (int qi = 0; qi < 4; ++qi)
#pragma unroll
    for (int nj = 0; nj < 4; ++nj) o[qi][nj] = (f32x4){0.f, 0.f, 0.f, 0.f};

  for (int t = 0; t < 32; ++t) {
    __syncthreads();  // drains tile-t staging
    if (t < 31) stage_kv(Kb, Vb, smem, tid, (t + 1) * 64, (t + 1) & 1);
    const unsigned short* Kd = smem + (t & 1) * 8192;
    const unsigned short* Vd = Kd + 4096;

#pragma unroll
    for (int blk = 0; blk < 2; ++blk) {
      // V B-frags: Vt[dh = nj*16+l15][s = blk*32 + quad*8 .. +7] — one b128 each
      bf16x8 vb[4];
#pragma unroll
      for (int nj = 0; nj < 4; ++nj) {
        int vrow = nj * 16 + l15;
        vb[nj] = *(const bf16x8*)(Vd + vrow * 64 + (((blk * 4 + quad) ^ rho(vrow)) * 8));
      }
      union { unsigned u[4]; bf16x8 v; } pa[4];
#pragma unroll
      for (int v = 0; v < 2; ++v) {
        // permuted K rows: C/D row m maps to s = blk*32 + 8*quad + 4*v + reg
        int krow = blk * 32 + 8 * (l15 >> 2) + 4 * v + (l15 & 3);
        const unsigned short* kr = Kd + krow * 64;
        bf16x8 ka0 = *(const bf16x8*)(kr + ((quad ^ rho(krow)) * 8));
        bf16x8 ka1 = *(const bf16x8*)(kr + (((4 + quad) ^ rho(krow)) * 8));
#pragma unroll
        for (int qi = 0; qi < 4; ++qi) {
          f32x4 S = (f32x4){0.f, 0.f, 0.f, 0.f};
          S = MFMA32(ka0, qf[qi][0], S, 0, 0, 0);
          S = MFMA32(ka1, qf[qi][1], S, 0, 0, 0);
          float e0 = EXP2(S[0]), e1 = EXP2(S[1]), e2 = EXP2(S[2]), e3 = EXP2(S[3]);
          l_part[qi] += (e0 + e1) + (e2 + e3);
          pa[qi].u[2 * v] = packbf2(e0, e1);
          pa[qi].u[2 * v + 1] = packbf2(e2, e3);
        }
      }
#pragma unroll
      for (int nj = 0; nj < 4; ++nj)
#pragma unroll
        for (int qi = 0; qi < 4; ++qi)
          o[qi][nj] = MFMA32(pa[qi].v, vb[nj], o[qi][nj], 0, 0, 0);
    }
  }

  // l: cross-quad reduce once; normalize + store
  const int b = bh >> 4, h = bh & 15;
#pragma unroll
  for (int qi = 0; qi < 4; ++qi) {
    float l = l_part[qi];
    l += __shfl_xor(l, 16);
    l += __shfl_xor(l, 32);
    float linv = 1.0f / l;
#pragma unroll
    for (int r = 0; r < 4; ++r) {
      float lr = __shfl(linv, 4 * quad + r);  // l of q_local = 4*quad + r
      int trow = qt * 256 + w * 64 + qi * 16 + 4 * quad + r;
#pragma unroll
      for (int nj = 0; nj < 4; ++nj) {
        int col = h * 64 + nj * 16 + l15;
        OH[((size_t)b * 2048 + trow) * 1024 + col] = f2bf(o[qi][nj][r] * lr);
      }
    }
  }
}

// ---------------- output projection ----------------
__global__ __launch_bounds__(256) void gemm_o(
    const unsigned short* __restrict__ OHm, const unsigned short* __restrict__ Wot,
    const float* __restrict__ bO, float* __restrict__ Out) {
  __shared__ unsigned short As[128 * 64];
  __shared__ unsigned short Bs[128 * 64];
  const int tid = threadIdx.x, lane = tid & 63, w = tid >> 6;
  const int quad = lane >> 4, l15 = lane & 15;
  const int wm = w & 1, wn = w >> 1;
  const int m0 = blockIdx.x * 128, n0 = blockIdx.y * 128;
  f32x4 acc[4][4];
#pragma unroll
  for (int i = 0; i < 4; ++i)
#pragma unroll
    for (int j = 0; j < 4; ++j) acc[i][j] = (f32x4){0.f, 0.f, 0.f, 0.f};

  gemm_mainloop_1024(OHm, Wot, As, Bs, m0, n0, acc);

#pragma unroll
  for (int nj = 0; nj < 4; ++nj) {
    const int n = n0 + wn * 64 + nj * 16 + l15;
    const float bv = bO[n];
#pragma unroll
    for (int mi = 0; mi < 4; ++mi) {
      const int mb = m0 + wm * 64 + mi * 16 + quad * 4;
#pragma unroll
      for (int r = 0; r < 4; ++r)
        Out[(size_t)(mb + r) * 1024 + n] = acc[mi][nj][r] + bv;
    }
  }
}

// ---------------- launch ----------------
extern "C" void kernel_launch(void* const* d_in, const int* in_sizes, int n_in,
                              void* d_out, int out_size, void* d_ws, size_t ws_size,
                              hipStream_t stream) {
  const float* x  = (const float*)d_in[0];
  const float* WQ = (const float*)d_in[1];
  const float* bQ = (const float*)d_in[2];
  const float* WK = (const float*)d_in[3];
  const float* bK = (const float*)d_in[4];
  const float* WV = (const float*)d_in[5];
  const float* bV = (const float*)d_in[6];
  const float* WO = (const float*)d_in[7];
  const float* bO = (const float*)d_in[8];
  float* out = (float*)d_out;

  char* ws = (char*)d_ws;
  unsigned short* Xb   = (unsigned short*)(ws);                // 16 MB
  unsigned short* OH   = (unsigned short*)(ws);                // alias (Xb dead)
  unsigned short* Wqkv = (unsigned short*)(ws + 16777216);     // 6 MB
  unsigned short* Wot  = (unsigned short*)(ws + 23068672);     // 2 MB
  unsigned short* Qg   = (unsigned short*)(ws + 25165824);     // 16 MB
  unsigned short* Kg   = (unsigned short*)(ws + 41943040);     // 16 MB
  unsigned int*   Vpg  = (unsigned int*)  (ws + 58720256);     // 16 MB

  prep_all<<<6144, 256, 0, stream>>>(x, WQ, WK, WV, WO, Xb, Wqkv, Wot);

  dim3 g1(64, 24);
  gemm_qkv<<<g1, 256, 0, stream>>>(Xb, Wqkv, bQ, bK, bV, Qg, Kg, Vpg);
  dim3 g2(8, 64);
  flash_attn<<<g2, 256, 0, stream>>>(Qg, Kg, Vpg, OH);
  dim3 g3(64, 8);
  gemm_o<<<g3, 256, 0, stream>>>(OH, Wot, bO, out);
}

// Round 8
// 258.420 us; speedup vs baseline: 1.1877x; 1.0573x over previous
//
#include <hip/hip_runtime.h>
#include <stdint.h>

// Attention fwd: B=4 T=2048 D=1024 H=16 Dh=64.
// R8: gemm_o retiled 128x64 -> grid 1024 = exactly 4 blocks/CU (was 512
// blocks = half-empty machine); flash grid transposed to (bh, qt) so all 8
// q-tiles of one bh land on one XCD (K/V becomes L2-local; R3 FETCH was
// 139MB vs 48MB inputs). gemm_qkv kept at R4/R7 form (measured local opt).

typedef __attribute__((ext_vector_type(8))) short bf16x8;
typedef __attribute__((ext_vector_type(4))) float f32x4;

#define MFMA32 __builtin_amdgcn_mfma_f32_16x16x32_bf16

#if __has_builtin(__builtin_amdgcn_exp2f)
#define EXP2(x) __builtin_amdgcn_exp2f(x)
#else
#define EXP2(x) exp2f(x)   // host pass only
#endif

__device__ __forceinline__ unsigned short f2bf(float f) {
  union { float f; unsigned int u; } v; v.f = f;
  unsigned int r = v.u + 0x7FFFu + ((v.u >> 16) & 1u);  // RNE
  return (unsigned short)(r >> 16);
}

__device__ __forceinline__ void gl_lds16(const void* g, void* l) {
  __builtin_amdgcn_global_load_lds(
      (const __attribute__((address_space(1))) unsigned int*)g,
      (__attribute__((address_space(3))) unsigned int*)l, 16, 0, 0);
}

// truncating pack of two positive fp32 -> one u32 (two bf16)
__device__ __forceinline__ unsigned packbf2(float lo, float hi) {
  union { float f; unsigned u; } a, b; a.f = lo; b.f = hi;
  return __builtin_amdgcn_perm(b.u, a.u, 0x07060302u);
}

// LDS chunk swizzle for K/V tiles (conflict-free for permuted-row b128 reads)
__device__ __forceinline__ int rho(int r) { return (r & 3) | ((r >> 1) & 4); }

// ---------------- merged prep kernel ----------------
__device__ __forceinline__ void conv8(const float* __restrict__ src,
                                      unsigned short* __restrict__ dst, int i) {
  const float4* sp = (const float4*)src;
  float4 a = sp[2 * i], b = sp[2 * i + 1];
  union { unsigned short u[8]; uint4 v; } o;
  o.u[0] = f2bf(a.x); o.u[1] = f2bf(a.y); o.u[2] = f2bf(a.z); o.u[3] = f2bf(a.w);
  o.u[4] = f2bf(b.x); o.u[5] = f2bf(b.y); o.u[6] = f2bf(b.z); o.u[7] = f2bf(b.w);
  ((uint4*)dst)[i] = o.v;
}

__global__ __launch_bounds__(256) void prep_all(
    const float* __restrict__ x, const float* __restrict__ WQ,
    const float* __restrict__ WK, const float* __restrict__ WV,
    const float* __restrict__ WO, unsigned short* __restrict__ Xb,
    unsigned short* __restrict__ Wqkv, unsigned short* __restrict__ Wot) {
  const int bx = blockIdx.x, t = threadIdx.x;
  if (bx < 4096) {
    conv8(x, Xb, bx * 256 + t);
  } else if (bx < 4608) {
    conv8(WQ, Wqkv, (bx - 4096) * 256 + t);
  } else if (bx < 5120) {
    conv8(WK, Wqkv + 1048576, (bx - 4608) * 256 + t);
  } else if (bx < 5632) {
    conv8(WV, Wqkv + 2097152, (bx - 5120) * 256 + t);
  } else {
    // W_O [16][1024][64] fp32 -> Wot [d][h*64+k] bf16
    int tid = (bx - 5632) * 256 + t;
    int h = tid >> 13, rem = tid & 8191;
    int d = rem >> 3, c = rem & 7;
    const float4* sp = (const float4*)(WO + (size_t)h * 65536 + d * 64 + c * 8);
    float4 a = sp[0], e = sp[1];
    union { unsigned short u[8]; uint4 v; } o;
    o.u[0] = f2bf(a.x); o.u[1] = f2bf(a.y); o.u[2] = f2bf(a.z); o.u[3] = f2bf(a.w);
    o.u[4] = f2bf(e.x); o.u[5] = f2bf(e.y); o.u[6] = f2bf(e.z); o.u[7] = f2bf(e.w);
    *(uint4*)(Wot + (size_t)d * 1024 + h * 64 + c * 8) = o.v;
  }
}

// ---------------- shared GEMM mainloop (128x128, for gemm_qkv) ----------------
__device__ __forceinline__ void gemm_mainloop_1024(
    const unsigned short* __restrict__ A, const unsigned short* __restrict__ B,
    unsigned short* As, unsigned short* Bs, int m0, int n0, f32x4 acc[4][4]) {
  const int tid = threadIdx.x;
  const int lane = tid & 63, w = tid >> 6;
  const int quad = lane >> 4, l15 = lane & 15;
  const int wm = w & 1, wn = w >> 1;
  int srow[4], scl[4];
#pragma unroll
  for (int u = 0; u < 4; ++u) {
    int s = u * 256 + tid;
    srow[u] = s >> 3;
    scl[u] = ((s & 7) ^ ((s >> 3) & 7)) * 8;
  }
  for (int k0 = 0; k0 < 1024; k0 += 64) {
    __syncthreads();
#pragma unroll
    for (int u = 0; u < 4; ++u) {
      int s = u * 256 + tid;
      gl_lds16(A + (size_t)(m0 + srow[u]) * 1024 + k0 + scl[u], As + s * 8);
      gl_lds16(B + (size_t)(n0 + srow[u]) * 1024 + k0 + scl[u], Bs + s * 8);
    }
    __syncthreads();
    bf16x8 af[4][2], bfr[4][2];
#pragma unroll
    for (int i = 0; i < 4; ++i) {
      int ra = wm * 64 + i * 16 + l15;
      int rb = wn * 64 + i * 16 + l15;
#pragma unroll
      for (int c = 0; c < 2; ++c) {
        af[i][c]  = *(const bf16x8*)(As + ra * 64 + (((c * 4 + quad) ^ (ra & 7)) * 8));
        bfr[i][c] = *(const bf16x8*)(Bs + rb * 64 + (((c * 4 + quad) ^ (rb & 7)) * 8));
      }
    }
#pragma unroll
    for (int mi = 0; mi < 4; ++mi)
#pragma unroll
      for (int nj = 0; nj < 4; ++nj) {
        acc[mi][nj] = MFMA32(af[mi][0], bfr[nj][0], acc[mi][nj], 0, 0, 0);
        acc[mi][nj] = MFMA32(af[mi][1], bfr[nj][1], acc[mi][nj], 0, 0, 0);
      }
  }
}

// ---------------- QKV projection (128x128 tile, R4 form) ----------------
__global__ __launch_bounds__(256) void gemm_qkv(
    const unsigned short* __restrict__ Xb, const unsigned short* __restrict__ Wqkv,
    const float* __restrict__ bQ, const float* __restrict__ bK,
    const float* __restrict__ bV, unsigned short* __restrict__ Qg,
    unsigned short* __restrict__ Kg, unsigned int* __restrict__ Vpg) {
  __shared__ unsigned short As[128 * 64];
  __shared__ unsigned short Bs[128 * 64];
  const int tid = threadIdx.x, lane = tid & 63, w = tid >> 6;
  const int quad = lane >> 4, l15 = lane & 15;
  const int wm = w & 1, wn = w >> 1;
  const int m0 = blockIdx.x * 128, n0 = blockIdx.y * 128;
  f32x4 acc[4][4];
#pragma unroll
  for (int i = 0; i < 4; ++i)
#pragma unroll
    for (int j = 0; j < 4; ++j) acc[i][j] = (f32x4){0.f, 0.f, 0.f, 0.f};

  gemm_mainloop_1024(Xb, Wqkv, As, Bs, m0, n0, acc);

  const int type = n0 >> 10;
  const int nreg = n0 & 1023;
  const float* bias = (type == 0) ? bQ : (type == 1) ? bK : bV;
#pragma unroll
  for (int nj = 0; nj < 4; ++nj) {
    const int n_loc = nreg + wn * 64 + nj * 16 + l15;
    const int h = n_loc >> 6, kh = n_loc & 63;
    const float bv = bias[n_loc];
#pragma unroll
    for (int mi = 0; mi < 4; ++mi) {
      const int mb = m0 + wm * 64 + mi * 16 + quad * 4;
      const int b = mb >> 11, tb = mb & 2047;
      if (type == 2) {
        uint2 pk;
        pk.x = (unsigned)f2bf(acc[mi][nj][0] + bv) |
               ((unsigned)f2bf(acc[mi][nj][1] + bv) << 16);
        pk.y = (unsigned)f2bf(acc[mi][nj][2] + bv) |
               ((unsigned)f2bf(acc[mi][nj][3] + bv) << 16);
        *(uint2*)(Vpg + ((size_t)(b * 16 + h) * 64 + kh) * 1024 + (tb >> 1)) = pk;
      } else {
        unsigned short* dst =
            ((type == 0) ? Qg : Kg) + ((size_t)(b * 16 + h) * 2048 + tb) * 64 + kh;
        // Q pre-scaled by 1/sqrt(Dh) * log2(e) so flash uses exp2 directly
        const float sc = (type == 0) ? 0.18033688011112042f : 1.0f;
        dst[0]   = f2bf((acc[mi][nj][0] + bv) * sc);
        dst[64]  = f2bf((acc[mi][nj][1] + bv) * sc);
        dst[128] = f2bf((acc[mi][nj][2] + bv) * sc);
        dst[192] = f2bf((acc[mi][nj][3] + bv) * sc);
      }
    }
  }
}

// ---------------- flash attention ----------------
__device__ __forceinline__ void stage_kv(const unsigned short* __restrict__ Kb,
                                         const unsigned int* __restrict__ Vb,
                                         unsigned short* smem, int tid, int s0, int b) {
#pragma unroll
  for (int u = 0; u < 2; ++u) {
    int s = u * 256 + tid, row = s >> 3, g = (s & 7) ^ rho(row);
    gl_lds16(Kb + (size_t)(s0 + row) * 64 + g * 8, smem + b * 8192 + s * 8);
    gl_lds16(Vb + (size_t)row * 1024 + (s0 >> 1) + g * 4,
             smem + b * 8192 + 4096 + s * 8);
  }
}

// block: 256 q-rows of one (b,h); wave owns 64 q; k-tiles of 64, double-buffered.
// grid (bh=64, qt=8): all q-tiles of one bh on one XCD -> K/V L2-local.
__global__ __launch_bounds__(256, 2) void flash_attn(
    const unsigned short* __restrict__ Qg, const unsigned short* __restrict__ Kg,
    const unsigned int* __restrict__ Vpg, unsigned short* __restrict__ OH) {
  __shared__ unsigned short smem[16384];  // 32KB: [K0 8K][V0 8K][K1 8K][V1 8K]
  const int tid = threadIdx.x, lane = tid & 63, w = tid >> 6;
  const int quad = lane >> 4, l15 = lane & 15;
  const int bh = blockIdx.x, qt = blockIdx.y;

  const unsigned short* Qb = Qg + ((size_t)bh * 2048 + qt * 256) * 64;
  const unsigned short* Kb = Kg + (size_t)bh * 2048 * 64;
  const unsigned int*  Vb = Vpg + (size_t)bh * 64 * 1024;

  // stage Q (256 rows = 32KB, whole smem) — dead before tile 0
#pragma unroll
  for (int u = 0; u < 8; ++u) {
    int s = u * 256 + tid, row = s >> 3;
    gl_lds16(Qb + row * 64 + ((s & 7) ^ (row & 7)) * 8, smem + s * 8);
  }
  __syncthreads();

  bf16x8 qf[4][2];  // B-operand Q frags, hoisted for whole kernel
#pragma unroll
  for (int qi = 0; qi < 4; ++qi) {
    int row = w * 64 + qi * 16 + l15;
#pragma unroll
    for (int c = 0; c < 2; ++c)
      qf[qi][c] = *(const bf16x8*)(smem + row * 64 + (((c * 4 + quad) ^ (row & 7)) * 8));
  }
  __syncthreads();  // all waves done reading Q; safe to overwrite with K0/V0

  stage_kv(Kb, Vb, smem, tid, 0, 0);

  f32x4 o[4][4];
  float l_part[4] = {0.f, 0.f, 0.f, 0.f};
#pragma unroll
  for (int qi = 0; qi < 4; ++qi)
#pragma unroll
    for (int nj = 0; nj < 4; ++nj) o[qi][nj] = (f32x4){0.f, 0.f, 0.f, 0.f};

  for (int t = 0; t < 32; ++t) {
    __syncthreads();  // drains tile-t staging
    if (t < 31) stage_kv(Kb, Vb, smem, tid, (t + 1) * 64, (t + 1) & 1);
    const unsigned short* Kd = smem + (t & 1) * 8192;
    const unsigned short* Vd = Kd + 4096;

#pragma unroll
    for (int blk = 0; blk < 2; ++blk) {
      // V B-frags: Vt[dh = nj*16+l15][s = blk*32 + quad*8 .. +7] — one b128 each
      bf16x8 vb[4];
#pragma unroll
      for (int nj = 0; nj < 4; ++nj) {
        int vrow = nj * 16 + l15;
        vb[nj] = *(const bf16x8*)(Vd + vrow * 64 + (((blk * 4 + quad) ^ rho(vrow)) * 8));
      }
      union { unsigned u[4]; bf16x8 v; } pa[4];
#pragma unroll
      for (int v = 0; v < 2; ++v) {
        // permuted K rows: C/D row m maps to s = blk*32 + 8*quad + 4*v + reg
        int krow = blk * 32 + 8 * (l15 >> 2) + 4 * v + (l15 & 3);
        const unsigned short* kr = Kd + krow * 64;
        bf16x8 ka0 = *(const bf16x8*)(kr + ((quad ^ rho(krow)) * 8));
        bf16x8 ka1 = *(const bf16x8*)(kr + (((4 + quad) ^ rho(krow)) * 8));
#pragma unroll
        for (int qi = 0; qi < 4; ++qi) {
          f32x4 S = (f32x4){0.f, 0.f, 0.f, 0.f};
          S = MFMA32(ka0, qf[qi][0], S, 0, 0, 0);
          S = MFMA32(ka1, qf[qi][1], S, 0, 0, 0);
          float e0 = EXP2(S[0]), e1 = EXP2(S[1]), e2 = EXP2(S[2]), e3 = EXP2(S[3]);
          l_part[qi] += (e0 + e1) + (e2 + e3);
          pa[qi].u[2 * v] = packbf2(e0, e1);
          pa[qi].u[2 * v + 1] = packbf2(e2, e3);
        }
      }
#pragma unroll
      for (int nj = 0; nj < 4; ++nj)
#pragma unroll
        for (int qi = 0; qi < 4; ++qi)
          o[qi][nj] = MFMA32(pa[qi].v, vb[nj], o[qi][nj], 0, 0, 0);
    }
  }

  // l: cross-quad reduce once; normalize + store
  const int b = bh >> 4, h = bh & 15;
#pragma unroll
  for (int qi = 0; qi < 4; ++qi) {
    float l = l_part[qi];
    l += __shfl_xor(l, 16);
    l += __shfl_xor(l, 32);
    float linv = 1.0f / l;
#pragma unroll
    for (int r = 0; r < 4; ++r) {
      float lr = __shfl(linv, 4 * quad + r);  // l of q_local = 4*quad + r
      int trow = qt * 256 + w * 64 + qi * 16 + 4 * quad + r;
#pragma unroll
      for (int nj = 0; nj < 4; ++nj) {
        int col = h * 64 + nj * 16 + l15;
        OH[((size_t)b * 2048 + trow) * 1024 + col] = f2bf(o[qi][nj][r] * lr);
      }
    }
  }
}

// ---------------- output projection (128x64 tile) ----------------
__global__ __launch_bounds__(256) void gemm_o(
    const unsigned short* __restrict__ OHm, const unsigned short* __restrict__ Wot,
    const float* __restrict__ bO, float* __restrict__ Out) {
  __shared__ unsigned short As[128 * 64];  // 16KB
  __shared__ unsigned short Bs[64 * 64];   // 8KB
  const int tid = threadIdx.x, lane = tid & 63, w = tid >> 6;
  const int quad = lane >> 4, l15 = lane & 15;
  const int wm = w & 1, wn = w >> 1;
  const int m0 = blockIdx.x * 128, n0 = blockIdx.y * 64;
  f32x4 acc[4][2];
#pragma unroll
  for (int i = 0; i < 4; ++i)
#pragma unroll
    for (int j = 0; j < 2; ++j) acc[i][j] = (f32x4){0.f, 0.f, 0.f, 0.f};

  for (int k0 = 0; k0 < 1024; k0 += 64) {
    __syncthreads();
#pragma unroll
    for (int u = 0; u < 4; ++u) {
      int s = u * 256 + tid, row = s >> 3;
      int cl = ((s & 7) ^ (row & 7)) * 8;
      gl_lds16(OHm + (size_t)(m0 + row) * 1024 + k0 + cl, As + s * 8);
    }
#pragma unroll
    for (int u = 0; u < 2; ++u) {
      int s = u * 256 + tid, row = s >> 3;
      int cl = ((s & 7) ^ (row & 7)) * 8;
      gl_lds16(Wot + (size_t)(n0 + row) * 1024 + k0 + cl, Bs + s * 8);
    }
    __syncthreads();
    bf16x8 af[4][2], bfr[2][2];
#pragma unroll
    for (int i = 0; i < 4; ++i) {
      int ra = wm * 64 + i * 16 + l15;
#pragma unroll
      for (int c = 0; c < 2; ++c)
        af[i][c] = *(const bf16x8*)(As + ra * 64 + (((c * 4 + quad) ^ (ra & 7)) * 8));
    }
#pragma unroll
    for (int j = 0; j < 2; ++j) {
      int rb = wn * 32 + j * 16 + l15;
#pragma unroll
      for (int c = 0; c < 2; ++c)
        bfr[j][c] = *(const bf16x8*)(Bs + rb * 64 + (((c * 4 + quad) ^ (rb & 7)) * 8));
    }
#pragma unroll
    for (int mi = 0; mi < 4; ++mi)
#pragma unroll
      for (int nj = 0; nj < 2; ++nj) {
        acc[mi][nj] = MFMA32(af[mi][0], bfr[nj][0], acc[mi][nj], 0, 0, 0);
        acc[mi][nj] = MFMA32(af[mi][1], bfr[nj][1], acc[mi][nj], 0, 0, 0);
      }
  }

#pragma unroll
  for (int nj = 0; nj < 2; ++nj) {
    const int n = n0 + wn * 32 + nj * 16 + l15;
    const float bv = bO[n];
#pragma unroll
    for (int mi = 0; mi < 4; ++mi) {
      const int mb = m0 + wm * 64 + mi * 16 + quad * 4;
#pragma unroll
      for (int r = 0; r < 4; ++r)
        Out[(size_t)(mb + r) * 1024 + n] = acc[mi][nj][r] + bv;
    }
  }
}

// ---------------- launch ----------------
extern "C" void kernel_launch(void* const* d_in, const int* in_sizes, int n_in,
                              void* d_out, int out_size, void* d_ws, size_t ws_size,
                              hipStream_t stream) {
  const float* x  = (const float*)d_in[0];
  const float* WQ = (const float*)d_in[1];
  const float* bQ = (const float*)d_in[2];
  const float* WK = (const float*)d_in[3];
  const float* bK = (const float*)d_in[4];
  const float* WV = (const float*)d_in[5];
  const float* bV = (const float*)d_in[6];
  const float* WO = (const float*)d_in[7];
  const float* bO = (const float*)d_in[8];
  float* out = (float*)d_out;

  char* ws = (char*)d_ws;
  unsigned short* Xb   = (unsigned short*)(ws);                // 16 MB
  unsigned short* OH   = (unsigned short*)(ws);                // alias (Xb dead)
  unsigned short* Wqkv = (unsigned short*)(ws + 16777216);     // 6 MB
  unsigned short* Wot  = (unsigned short*)(ws + 23068672);     // 2 MB
  unsigned short* Qg   = (unsigned short*)(ws + 25165824);     // 16 MB
  unsigned short* Kg   = (unsigned short*)(ws + 41943040);     // 16 MB
  unsigned int*   Vpg  = (unsigned int*)  (ws + 58720256);     // 16 MB

  prep_all<<<6144, 256, 0, stream>>>(x, WQ, WK, WV, WO, Xb, Wqkv, Wot);

  dim3 g1(64, 24);
  gemm_qkv<<<g1, 256, 0, stream>>>(Xb, Wqkv, bQ, bK, bV, Qg, Kg, Vpg);
  dim3 g2(64, 8);
  flash_attn<<<g2, 256, 0, stream>>>(Qg, Kg, Vpg, OH);
  dim3 g3(64, 16);
  gemm_o<<<g3, 256, 0, stream>>>(OH, Wot, bO, out);
}